// Round 5
// baseline (2793.010 us; speedup 1.0000x reference)
//
#include <hip/hip_runtime.h>

// HarmonicRNN: enc GRU (T=32, in=16000, H=512) -> dec GRU (510 steps, in=6) + linear(6).
// k0: zero out, seed gi with enc_b_ih, warm LLC with both w_hh matrices.
// k1: gi[t][row] = enc_w_ih @ x_t (+bias), K-split GEMM with atomicAdd.
// k2: persistent 16-WG kernel. 12 compute waves (matvec, w[8][8] in regs) +
//     1 control wave (gates, msg gather, publish). Cross-WG exchange via
//     SELF-TAGGED 64-bit RELAXED agent atomics: word = (tag<<32)|payload.
//     No acquire/release anywhere -> no buffer_inv/wbl2 storms, L2 stays warm.

#define HID 512
#define G3  1536
#define NWG 16
#define TPB 832   // 12 compute waves (768 threads) + 1 control wave (64)
#define JPW 32    // h indices per WG

typedef unsigned long long u64;
typedef unsigned int u32;

// ws layout:
//   u64 hexT[2][512]      : u64 idx 0..1023      (bytes 0..8191)
//   u64 pmsgT[2][16][8]   : u64 idx 1024..1279   (bytes 8192..10239)
//   float sink            : float idx 3800
//   float gi_enc[32][1536]: float idx 4096..
#define WS_GI   4096
#define WS_SINK 3800

__device__ __forceinline__ float sigmf(float x) { return 1.0f / (1.0f + __expf(-x)); }

__device__ __forceinline__ u64 ld64(const u64* p) {
  return __hip_atomic_load(p, __ATOMIC_RELAXED, __HIP_MEMORY_SCOPE_AGENT);
}
__device__ __forceinline__ void st64(u64* p, u64 v) {
  __hip_atomic_store(p, v, __ATOMIC_RELAXED, __HIP_MEMORY_SCOPE_AGENT);
}

__global__ __launch_bounds__(256) void k0_init(float* __restrict__ ws, float* __restrict__ out,
                                               const float* __restrict__ enc_b_ih,
                                               const float* __restrict__ enc_w_hh,
                                               const float* __restrict__ dec_w_hh) {
  int i = blockIdx.x * 256 + threadIdx.x;
  int n = gridDim.x * 256;
  for (int j = i; j < 3073; j += n) out[j] = 0.0f;
  for (int j = i; j < 32 * G3; j += n) ws[WS_GI + j] = enc_b_ih[j % G3];
  // warm LLC with recurrent weights (3 MB each)
  float s = 0.f;
  const float4* a = (const float4*)enc_w_hh;
  const float4* b = (const float4*)dec_w_hh;
  for (int j = i; j < G3 * HID / 4; j += n) {
    float4 u = a[j], v = b[j];
    s += u.x + u.y + u.z + u.w + v.x + v.y + v.z + v.w;
  }
  if (s == 1234567.8f) ws[WS_SINK] = s;  // never true; keeps loads alive
}

#define KB 160
__global__ __launch_bounds__(256) void k1_gemm(const float* __restrict__ x,
                                               const float* __restrict__ wih,
                                               float* __restrict__ ws) {
  __shared__ float lw[64][KB + 4];
  __shared__ float lx[32][KB + 4];
  const int m0  = blockIdx.x * 64;     // 24 row blocks
  const int k00 = blockIdx.y * 1600;   // 10 K splits
  const int t   = threadIdx.x;
  const int rg  = t >> 4;              // 16 row groups of 4
  const int tg  = t & 15;              // 16 t groups of 2
  float acc[4][2] = {{0.f,0.f},{0.f,0.f},{0.f,0.f},{0.f,0.f}};
  for (int c = 0; c < 10; ++c) {
    const int kc = k00 + c * KB;
    __syncthreads();
    #pragma unroll
    for (int j = 0; j < 10; ++j) {
      int idx = t + j * 256;
      int r = idx / 40, c4 = idx % 40;
      float4 v = *reinterpret_cast<const float4*>(wih + (long)(m0 + r) * 16000 + kc + c4 * 4);
      *reinterpret_cast<float4*>(&lw[r][c4 * 4]) = v;
    }
    #pragma unroll
    for (int j = 0; j < 5; ++j) {
      int idx = t + j * 256;
      int r = idx / 40, c4 = idx % 40;
      float4 v = *reinterpret_cast<const float4*>(x + (long)r * 16000 + kc + c4 * 4);
      *reinterpret_cast<float4*>(&lx[r][c4 * 4]) = v;
    }
    __syncthreads();
    for (int kk = 0; kk < KB; kk += 4) {
      float4 xv0 = *reinterpret_cast<const float4*>(&lx[tg * 2 + 0][kk]);
      float4 xv1 = *reinterpret_cast<const float4*>(&lx[tg * 2 + 1][kk]);
      #pragma unroll
      for (int j = 0; j < 4; ++j) {
        float4 wv = *reinterpret_cast<const float4*>(&lw[rg * 4 + j][kk]);
        acc[j][0] += wv.x * xv0.x + wv.y * xv0.y + wv.z * xv0.z + wv.w * xv0.w;
        acc[j][1] += wv.x * xv1.x + wv.y * xv1.y + wv.z * xv1.z + wv.w * xv1.w;
      }
    }
  }
  #pragma unroll
  for (int j = 0; j < 4; ++j)
    #pragma unroll
    for (int u = 0; u < 2; ++u)
      atomicAdd(&ws[WS_GI + (tg * 2 + u) * G3 + m0 + rg * 4 + j], acc[j][u]);
}

__device__ __forceinline__ void load_w(const float* __restrict__ whh, int j0, int rg, int cg,
                                       float w[8][8]) {
  #pragma unroll
  for (int i2 = 0; i2 < 8; ++i2) {
    const int r = rg * 8 + i2;                       // local row 0..95
    const int grow = (r >> 5) * HID + j0 + (r & 31); // gate*512 + j0 + j
    const float* src = whh + grow * HID + cg;        // cols cg + 64u
    #pragma unroll
    for (int u = 0; u < 8; ++u) w[i2][u] = src[64 * u];
  }
}

// poll 8 self-tagged h words (cols cg+64u). returns true if brk flag seen.
__device__ __forceinline__ bool poll_h(const u64* hb, u32 want, float hr[8],
                                       const int* brk_p, bool escape) {
  u64 v[8];
  #pragma unroll
  for (int u = 0; u < 8; ++u) v[u] = ld64(hb + 64 * u);
  for (;;) {
    bool all = true;
    #pragma unroll
    for (int u = 0; u < 8; ++u) all = all && ((u32)(v[u] >> 32) == want);
    if (all) break;
    if (escape && __hip_atomic_load(brk_p, __ATOMIC_RELAXED, __HIP_MEMORY_SCOPE_WORKGROUP))
      return true;
    __builtin_amdgcn_s_sleep(1);
    #pragma unroll
    for (int u = 0; u < 8; ++u)
      if ((u32)(v[u] >> 32) != want) v[u] = ld64(hb + 64 * u);
  }
  #pragma unroll
  for (int u = 0; u < 8; ++u) hr[u] = __uint_as_float((u32)v[u]);
  return false;
}

__global__ __launch_bounds__(TPB, 1) void k2_rnn(
    const float* __restrict__ enc_w_hh, const float* __restrict__ enc_b_hh,
    const float* __restrict__ dec_w_ih, const float* __restrict__ dec_w_hh,
    const float* __restrict__ dec_b_ih, const float* __restrict__ dec_b_hh,
    const float* __restrict__ lin_w, const float* __restrict__ lin_b,
    float* __restrict__ ws, float* __restrict__ out) {
  __shared__ float gsum[2][96];
  __shared__ int s_brk;

  const int wg = blockIdx.x;
  const int t  = threadIdx.x;
  const int j0 = wg * JPW;

  u64* hexT = (u64*)ws;          // [2][512]
  u64* pmT  = hexT + 1024;       // [2][16][8]
  const float* gi_enc = ws + WS_GI;

  if (t < 768) {
    // ================= compute waves: 96x512 matvec =================
    const int rg = t >> 6;   // 12 rgroups of 8 rows
    const int cg = t & 63;   // cols cg + 64u
    float w[8][8];
    load_w(enc_w_hh, j0, rg, cg, w);

    for (int s = 0; s < 32; ++s) {
      float hr[8];
      if (s == 0) {
        #pragma unroll
        for (int u = 0; u < 8; ++u) hr[u] = 0.f;
      } else {
        const u32 want = (u32)s;
        poll_h(hexT + (want & 1) * 512 + cg, want, hr, &s_brk, false);
      }
      float acc[8];
      #pragma unroll
      for (int i2 = 0; i2 < 8; ++i2) {
        float a = 0.f;
        #pragma unroll
        for (int u = 0; u < 8; ++u) a = fmaf(w[i2][u], hr[u], a);
        acc[i2] = a;
      }
      #pragma unroll
      for (int m = 1; m <= 32; m <<= 1) {
        #pragma unroll
        for (int i2 = 0; i2 < 8; ++i2) acc[i2] += __shfl_xor(acc[i2], m, 64);
      }
      if (cg == 0) {
        #pragma unroll
        for (int i2 = 0; i2 < 8; ++i2) gsum[s & 1][rg * 8 + i2] = acc[i2];
      }
      __syncthreads();
    }

    load_w(dec_w_hh, j0, rg, cg, w);
    __syncthreads();  // stage-B setup barrier

    for (int k = 0; k <= 510; ++k) {
      const u32 want = 32u + (u32)k;
      float hr[8];
      if (poll_h(hexT + (want & 1) * 512 + cg, want, hr, &s_brk, true)) break;
      float acc[8];
      #pragma unroll
      for (int i2 = 0; i2 < 8; ++i2) {
        float a = 0.f;
        #pragma unroll
        for (int u = 0; u < 8; ++u) a = fmaf(w[i2][u], hr[u], a);
        acc[i2] = a;
      }
      #pragma unroll
      for (int m = 1; m <= 32; m <<= 1) {
        #pragma unroll
        for (int i2 = 0; i2 < 8; ++i2) acc[i2] += __shfl_xor(acc[i2], m, 64);
      }
      if (cg == 0) {
        #pragma unroll
        for (int i2 = 0; i2 < 8; ++i2) gsum[k & 1][rg * 8 + i2] = acc[i2];
      }
      __syncthreads();
    }
  } else {
    // ================= control wave: gates + gather + publish =================
    const int lane = t - 768;
    float hreg = 0.f;
    float eb0 = 0, eb1 = 0, eb2 = 0;
    if (lane < 32) {
      eb0 = enc_b_hh[j0 + lane];
      eb1 = enc_b_hh[HID + j0 + lane];
      eb2 = enc_b_hh[2 * HID + j0 + lane];
    }
    // -------- encoder --------
    for (int s = 0; s < 32; ++s) {
      float gi0 = 0, gi1 = 0, gi2 = 0;
      if (lane < 32) {
        const float* g = gi_enc + s * G3 + j0 + lane;
        gi0 = g[0]; gi1 = g[HID]; gi2 = g[2 * HID];
      }
      __syncthreads();
      if (lane < 32) {
        const float* gs = gsum[s & 1];
        float rr = sigmf(gi0 + gs[lane] + eb0);
        float zz = sigmf(gi1 + gs[32 + lane] + eb1);
        float ee = __expf(-2.f * (gi2 + rr * (gs[64 + lane] + eb2)));
        float nn = (1.f - ee) / (1.f + ee);
        hreg = (1.f - zz) * nn + zz * hreg;
        const u32 tg = (u32)s + 1u;
        st64(&hexT[(tg & 1) * 512 + j0 + lane], ((u64)tg << 32) | (u64)__float_as_uint(hreg));
      }
    }
    // -------- decoder setup --------
    float di0 = 0, di1 = 0, di2 = 0, dh0 = 0, dh1 = 0, dh2 = 0;
    float wr[6], wz[6], wn[6], lw[6], lb[6];
    #pragma unroll
    for (int m = 0; m < 6; ++m) { wr[m]=0; wz[m]=0; wn[m]=0; lw[m]=0; lb[m]=0; }
    if (lane < 32) {
      const int jr = j0 + lane;
      di0 = dec_b_ih[jr]; di1 = dec_b_ih[HID + jr]; di2 = dec_b_ih[2 * HID + jr];
      dh0 = dec_b_hh[jr]; dh1 = dec_b_hh[HID + jr]; dh2 = dec_b_hh[2 * HID + jr];
      #pragma unroll
      for (int m = 0; m < 6; ++m) {
        wr[m] = dec_w_ih[jr * 6 + m];
        wz[m] = dec_w_ih[(HID + jr) * 6 + m];
        wn[m] = dec_w_ih[(2 * HID + jr) * 6 + m];
        lw[m] = lin_w[m * HID + jr];
      }
    }
    if (lane >= 32 && lane < 48) {
      #pragma unroll
      for (int m = 0; m < 6; ++m) lb[m] = lin_b[m];
    }
    if (lane == 32) s_brk = 0;
    __syncthreads();  // stage-B setup barrier

    int messages = 1, pendrow = 0;
    bool pend = false, alive = true;

    for (int k = 0; k <= 510 && alive; ++k) {
      float m0 = 0, m1 = 0, m2 = 0, m3 = 0, m4 = 0, m5 = 0;
      bool cond = true;
      if (k >= 1) {
        const u32 want = 32u + (u32)k;
        float g0 = 0, g1 = 0, g2 = 0, g3 = 0, g4 = 0, g5 = 0;
        if (lane >= 32 && lane < 48) {
          const u64* pb = pmT + (want & 1) * 128 + (lane - 32) * 8;
          u64 v[6];
          #pragma unroll
          for (int m = 0; m < 6; ++m) v[m] = ld64(pb + m);
          for (;;) {
            bool all = true;
            #pragma unroll
            for (int m = 0; m < 6; ++m) all = all && ((u32)(v[m] >> 32) == want);
            if (all) break;
            __builtin_amdgcn_s_sleep(1);
            #pragma unroll
            for (int m = 0; m < 6; ++m)
              if ((u32)(v[m] >> 32) != want) v[m] = ld64(pb + m);
          }
          g0 = __uint_as_float((u32)v[0]); g1 = __uint_as_float((u32)v[1]);
          g2 = __uint_as_float((u32)v[2]); g3 = __uint_as_float((u32)v[3]);
          g4 = __uint_as_float((u32)v[4]); g5 = __uint_as_float((u32)v[5]);
          #pragma unroll
          for (int mm = 1; mm <= 8; mm <<= 1) {
            g0 += __shfl_xor(g0, mm, 64); g1 += __shfl_xor(g1, mm, 64);
            g2 += __shfl_xor(g2, mm, 64); g3 += __shfl_xor(g3, mm, 64);
            g4 += __shfl_xor(g4, mm, 64); g5 += __shfl_xor(g5, mm, 64);
          }
          g0 += lb[0]; g1 += lb[1]; g2 += lb[2]; g3 += lb[3]; g4 += lb[4]; g5 += lb[5];
        }
        m0 = __shfl(g0, 32, 64); m1 = __shfl(g1, 32, 64); m2 = __shfl(g2, 32, 64);
        m3 = __shfl(g3, 32, 64); m4 = __shfl(g4, 32, 64); m5 = __shfl(g5, 32, 64);
        if (pend && wg == 0 && lane == 32) {
          float* o = out + pendrow * 6;
          o[0] = m0; o[1] = m1; o[2] = m2; o[3] = m3; o[4] = m4; o[5] = m5;
        }
        cond = (rintf(m0) != 2.0f) && (messages < 511);
      }
      __syncthreads();  // barrier A (gsum ready)
      if (cond) {
        if (lane < 32) {
          float gi0 = di0, gi1 = di1, gi2 = di2;
          if (k >= 1) {
            gi0 += wr[0]*m0 + wr[1]*m1 + wr[2]*m2 + wr[3]*m3 + wr[4]*m4 + wr[5]*m5;
            gi1 += wz[0]*m0 + wz[1]*m1 + wz[2]*m2 + wz[3]*m3 + wz[4]*m4 + wz[5]*m5;
            gi2 += wn[0]*m0 + wn[1]*m1 + wn[2]*m2 + wn[3]*m3 + wn[4]*m4 + wn[5]*m5;
          }
          const float* gs = gsum[k & 1];
          float rr = sigmf(gi0 + gs[lane] + dh0);
          float zz = sigmf(gi1 + gs[32 + lane] + dh1);
          float ee = __expf(-2.f * (gi2 + rr * (gs[64 + lane] + dh2)));
          float nn = (1.f - ee) / (1.f + ee);
          hreg = (1.f - zz) * nn + zz * hreg;
          const u32 tg = 33u + (u32)k;
          st64(&hexT[(tg & 1) * 512 + j0 + lane], ((u64)tg << 32) | (u64)__float_as_uint(hreg));
          float c0 = lw[0]*hreg, c1 = lw[1]*hreg, c2 = lw[2]*hreg;
          float c3 = lw[3]*hreg, c4 = lw[4]*hreg, c5 = lw[5]*hreg;
          #pragma unroll
          for (int mm = 1; mm <= 16; mm <<= 1) {
            c0 += __shfl_xor(c0, mm, 64); c1 += __shfl_xor(c1, mm, 64);
            c2 += __shfl_xor(c2, mm, 64); c3 += __shfl_xor(c3, mm, 64);
            c4 += __shfl_xor(c4, mm, 64); c5 += __shfl_xor(c5, mm, 64);
          }
          if (lane == 0) {
            u64* pb = pmT + (tg & 1) * 128 + wg * 8;
            st64(pb + 0, ((u64)tg << 32) | (u64)__float_as_uint(c0));
            st64(pb + 1, ((u64)tg << 32) | (u64)__float_as_uint(c1));
            st64(pb + 2, ((u64)tg << 32) | (u64)__float_as_uint(c2));
            st64(pb + 3, ((u64)tg << 32) | (u64)__float_as_uint(c3));
            st64(pb + 4, ((u64)tg << 32) | (u64)__float_as_uint(c4));
            st64(pb + 5, ((u64)tg << 32) | (u64)__float_as_uint(c5));
          }
        }
        if (k >= 1) ++messages;
        pendrow = (k == 0) ? 0 : messages;
        pend = true;
      } else {
        if (lane == 32)
          __hip_atomic_store(&s_brk, 1, __ATOMIC_RELAXED, __HIP_MEMORY_SCOPE_WORKGROUP);
        pend = false;
        alive = false;
      }
    }

    // epilogue: gather + write the final pending msg (tag 543, row 511)
    if (pend && wg == 0) {
      const u32 want = 543u;
      float g0 = 0, g1 = 0, g2 = 0, g3 = 0, g4 = 0, g5 = 0;
      if (lane >= 32 && lane < 48) {
        const u64* pb = pmT + (want & 1) * 128 + (lane - 32) * 8;
        u64 v[6];
        #pragma unroll
        for (int m = 0; m < 6; ++m) v[m] = ld64(pb + m);
        for (;;) {
          bool all = true;
          #pragma unroll
          for (int m = 0; m < 6; ++m) all = all && ((u32)(v[m] >> 32) == want);
          if (all) break;
          __builtin_amdgcn_s_sleep(1);
          #pragma unroll
          for (int m = 0; m < 6; ++m)
            if ((u32)(v[m] >> 32) != want) v[m] = ld64(pb + m);
        }
        g0 = __uint_as_float((u32)v[0]); g1 = __uint_as_float((u32)v[1]);
        g2 = __uint_as_float((u32)v[2]); g3 = __uint_as_float((u32)v[3]);
        g4 = __uint_as_float((u32)v[4]); g5 = __uint_as_float((u32)v[5]);
        #pragma unroll
        for (int mm = 1; mm <= 8; mm <<= 1) {
          g0 += __shfl_xor(g0, mm, 64); g1 += __shfl_xor(g1, mm, 64);
          g2 += __shfl_xor(g2, mm, 64); g3 += __shfl_xor(g3, mm, 64);
          g4 += __shfl_xor(g4, mm, 64); g5 += __shfl_xor(g5, mm, 64);
        }
        g0 += lb[0]; g1 += lb[1]; g2 += lb[2]; g3 += lb[3]; g4 += lb[4]; g5 += lb[5];
        if (lane == 32) {
          float* o = out + pendrow * 6;
          o[0] = g0; o[1] = g1; o[2] = g2; o[3] = g3; o[4] = g4; o[5] = g5;
        }
      }
    }
    if (wg == 0 && lane == 32) out[3072] = (float)(messages + 1);
  }
}

extern "C" void kernel_launch(void* const* d_in, const int* in_sizes, int n_in,
                              void* d_out, int out_size, void* d_ws, size_t ws_size,
                              hipStream_t stream) {
  const float* x        = (const float*)d_in[0];
  const float* enc_w_ih = (const float*)d_in[1];
  const float* enc_w_hh = (const float*)d_in[2];
  const float* enc_b_ih = (const float*)d_in[3];
  const float* enc_b_hh = (const float*)d_in[4];
  const float* dec_w_ih = (const float*)d_in[5];
  const float* dec_w_hh = (const float*)d_in[6];
  const float* dec_b_ih = (const float*)d_in[7];
  const float* dec_b_hh = (const float*)d_in[8];
  const float* lin_w    = (const float*)d_in[9];
  const float* lin_b    = (const float*)d_in[10];
  float* ws  = (float*)d_ws;
  float* out = (float*)d_out;

  hipLaunchKernelGGL(k0_init, dim3(64), dim3(256), 0, stream, ws, out, enc_b_ih, enc_w_hh, dec_w_hh);
  hipLaunchKernelGGL(k1_gemm, dim3(24, 10), dim3(256), 0, stream, x, enc_w_ih, ws);
  hipLaunchKernelGGL(k2_rnn, dim3(NWG), dim3(TPB), 0, stream,
                     enc_w_hh, enc_b_hh, dec_w_ih, dec_w_hh, dec_b_ih, dec_b_hh,
                     lin_w, lin_b, ws, out);
}